// Round 1
// baseline (258.912 us; speedup 1.0000x reference)
//
#include <hip/hip_runtime.h>

#define NQ 4096
#define MK 4096
#define DKC 512
#define DVC 512
#define SCALE 0.044151079f  // 1/sqrt(513)

typedef __attribute__((ext_vector_type(8))) short short8;
typedef __attribute__((ext_vector_type(4))) float f32x4;

__device__ __forceinline__ unsigned short f2bf(float x) {
  unsigned u = __float_as_uint(x);
  u += 0x7fffu + ((u >> 16) & 1u);
  return (unsigned short)(u >> 16);
}

// ---------------- prep: query -> bf16, q_att = rowdot(query, q_k) ----------------
__global__ void prep_q(const float* __restrict__ query, const float* __restrict__ q_k,
                       unsigned short* __restrict__ Qb, float* __restrict__ qatt) {
  int n = blockIdx.x * 4 + (threadIdx.x >> 6);
  int lane = threadIdx.x & 63;
  const float4* qr = (const float4*)(query + (size_t)n * DKC + lane * 8);
  const float4* kr = (const float4*)(q_k + (size_t)n * DKC + lane * 8);
  float4 a0 = qr[0], a1 = qr[1];
  float4 b0 = kr[0], b1 = kr[1];
  float dot = a0.x * b0.x + a0.y * b0.y + a0.z * b0.z + a0.w * b0.w +
              a1.x * b1.x + a1.y * b1.y + a1.z * b1.z + a1.w * b1.w;
  unsigned short h[8] = {f2bf(a0.x), f2bf(a0.y), f2bf(a0.z), f2bf(a0.w),
                         f2bf(a1.x), f2bf(a1.y), f2bf(a1.z), f2bf(a1.w)};
  *(short8*)(Qb + (size_t)n * DKC + lane * 8) = *(short8*)h;
#pragma unroll
  for (int off = 1; off < 64; off <<= 1) dot += __shfl_xor(dot, off, 64);
  if (lane == 0) qatt[n] = dot;
}

// ---------------- prep: key -> bf16 ----------------
__global__ void prep_k(const float* __restrict__ key, unsigned short* __restrict__ Kb) {
  int i = blockIdx.x * blockDim.x + threadIdx.x;  // one per 8 elements
  const float4* src = (const float4*)key + (size_t)i * 2;
  float4 a0 = src[0], a1 = src[1];
  unsigned short h[8] = {f2bf(a0.x), f2bf(a0.y), f2bf(a0.z), f2bf(a0.w),
                         f2bf(a1.x), f2bf(a1.y), f2bf(a1.z), f2bf(a1.w)};
  *(short8*)(Kb + (size_t)i * 8) = *(short8*)h;
}

// ---------------- prep: value -> bf16 transposed Vt[d][m] ----------------
__global__ void prep_vt(const float* __restrict__ value, unsigned short* __restrict__ Vt) {
  __shared__ float t[32][33];
  int tx = threadIdx.x & 31, ty = threadIdx.x >> 5;  // 32x8
  int m0 = blockIdx.x * 32;
  int d0 = blockIdx.y * 32;
#pragma unroll
  for (int i = 0; i < 4; ++i)
    t[ty + i * 8][tx] = value[(size_t)(m0 + ty + i * 8) * DVC + d0 + tx];
  __syncthreads();
#pragma unroll
  for (int i = 0; i < 4; ++i)
    Vt[(size_t)(d0 + ty + i * 8) * MK + m0 + tx] = f2bf(t[tx][ty + i * 8]);
}

// ---------------- attention partials: grid = 32 qb x 8 mc ----------------
__global__ __launch_bounds__(512, 2) void attn_partial(
    const unsigned short* __restrict__ Qb, const unsigned short* __restrict__ Kb,
    const unsigned short* __restrict__ Vt, float* __restrict__ part_O,
    float* __restrict__ part_m, float* __restrict__ part_l) {
  __shared__ __align__(16) char k_lds[32768];                 // [32 keys][512 dk] bf16, swizzled
  __shared__ __align__(16) char v_lds[32768];                 // [512 d][32 keys] bf16, swizzled
  __shared__ __align__(16) unsigned short p_lds[8][16][32];   // per-wave P tile

  const int tid = threadIdx.x;
  const int wid = tid >> 6;
  const int lane = tid & 63;
  const int lr = lane & 15;
  const int lh = lane >> 4;

  const int qb = blockIdx.x >> 3;
  const int mc = blockIdx.x & 7;
  const int qrow0 = qb * 128 + wid * 16;

  // Q fragments: A[row=lr][k = kk*32 + lh*8 + j]
  short8 qf[16];
  {
    const short8* qp = (const short8*)(Qb + (size_t)(qrow0 + lr) * DKC);
#pragma unroll
    for (int kk = 0; kk < 16; ++kk) qf[kk] = qp[kk * 4 + lh];
  }

  float m[4] = {-1e30f, -1e30f, -1e30f, -1e30f};
  float lsum[4] = {0.f, 0.f, 0.f, 0.f};
  f32x4 acc[32];
#pragma unroll
  for (int i = 0; i < 32; ++i) acc[i] = (f32x4){0.f, 0.f, 0.f, 0.f};

  const char* kbase = (const char*)Kb + (size_t)mc * 512 * DKC * 2;
  const char* vbase = (const char*)Vt;

  for (int c = 0; c < 16; ++c) {
    // ---- stage K chunk (32KB) + V chunk (32KB), swizzled source, linear LDS ----
    {
      const char* kg = kbase + (size_t)c * 32 * DKC * 2;
      const size_t vcol = (size_t)(mc * 512 + c * 32) * 2;
#pragma unroll
      for (int s = 0; s < 4; ++s) {
        int o = s * 8192 + tid * 16;
        int srck = o ^ (((o >> 10) & 7) << 4);
        *(uint4*)(k_lds + o) = *(const uint4*)(kg + srck);
        int lv = o ^ (((o >> 7) & 3) << 4);
        int d = lv >> 6, ib = lv & 63;
        *(uint4*)(v_lds + o) = *(const uint4*)(vbase + (size_t)d * (MK * 2) + vcol + ib);
      }
    }
    __syncthreads();

    // ---- S = Q * Kc^T : two 16x16 tiles over K=512 ----
    f32x4 sa0 = {0.f, 0.f, 0.f, 0.f}, sa1 = {0.f, 0.f, 0.f, 0.f};
#pragma unroll
    for (int kk = 0; kk < 16; ++kk) {
      int b0 = (lr * 1024 + kk * 64 + lh * 16) ^ ((lr & 7) << 4);
      int b1 = ((16 + lr) * 1024 + kk * 64 + lh * 16) ^ ((lr & 7) << 4);
      short8 kf0 = *(const short8*)(k_lds + b0);
      short8 kf1 = *(const short8*)(k_lds + b1);
      sa0 = __builtin_amdgcn_mfma_f32_16x16x32_bf16(qf[kk], kf0, sa0, 0, 0, 0);
      sa1 = __builtin_amdgcn_mfma_f32_16x16x32_bf16(qf[kk], kf1, sa1, 0, 0, 0);
    }

    // ---- online softmax (rows = lh*4+r, keys = lr and 16+lr) ----
    float sv0[4], sv1[4], rmax[4];
#pragma unroll
    for (int r = 0; r < 4; ++r) {
      sv0[r] = sa0[r] * SCALE;
      sv1[r] = sa1[r] * SCALE;
      rmax[r] = fmaxf(sv0[r], sv1[r]);
    }
#pragma unroll
    for (int off = 1; off < 16; off <<= 1)
#pragma unroll
      for (int r = 0; r < 4; ++r) rmax[r] = fmaxf(rmax[r], __shfl_xor(rmax[r], off, 64));
    float alpha[4];
    bool need = false;
#pragma unroll
    for (int r = 0; r < 4; ++r) {
      float nm = fmaxf(m[r], rmax[r]);
      alpha[r] = __expf(m[r] - nm);
      m[r] = nm;
      need = need || (alpha[r] != 1.0f);
    }
    if (__any(need)) {
#pragma unroll
      for (int dt = 0; dt < 32; ++dt)
#pragma unroll
        for (int r = 0; r < 4; ++r) acc[dt][r] *= alpha[r];
#pragma unroll
      for (int r = 0; r < 4; ++r) lsum[r] *= alpha[r];
    }
#pragma unroll
    for (int r = 0; r < 4; ++r) {
      float p0 = __expf(sv0[r] - m[r]);
      float p1 = __expf(sv1[r] - m[r]);
      lsum[r] += p0 + p1;
      p_lds[wid][lh * 4 + r][lr] = f2bf(p0);
      p_lds[wid][lh * 4 + r][16 + lr] = f2bf(p1);
    }
    // A-frag of P: row=lr, k = lh*8+j (same-wave LDS, DS unit is in-order)
    short8 pf = *(const short8*)(&p_lds[wid][lr][lh * 8]);

    // ---- O += P * Vc over 32 d-tiles ----
#pragma unroll
    for (int dt = 0; dt < 32; ++dt) {
      int d = dt * 16 + lr;
      int b = (d * 64 + lh * 16) ^ (((d >> 1) & 3) << 4);
      short8 vf = *(const short8*)(v_lds + b);
      acc[dt] = __builtin_amdgcn_mfma_f32_16x16x32_bf16(pf, vf, acc[dt], 0, 0, 0);
    }
    __syncthreads();
  }

  // ---- finalize: reduce lsum across the 16 key-lanes ----
#pragma unroll
  for (int off = 1; off < 16; off <<= 1)
#pragma unroll
    for (int r = 0; r < 4; ++r) lsum[r] += __shfl_xor(lsum[r], off, 64);

  if (lr == 0) {
#pragma unroll
    for (int r = 0; r < 4; ++r) {
      int row = qrow0 + lh * 4 + r;
      part_m[(size_t)mc * NQ + row] = m[r];
      part_l[(size_t)mc * NQ + row] = lsum[r];
    }
  }
#pragma unroll
  for (int dt = 0; dt < 32; ++dt)
#pragma unroll
    for (int r = 0; r < 4; ++r) {
      int row = qrow0 + lh * 4 + r;
      part_O[((size_t)mc * NQ + row) * DVC + dt * 16 + lr] = acc[dt][r];
    }
}

// ---------------- combine partials + epilogue ----------------
__global__ void combine(const float* __restrict__ part_O, const float* __restrict__ part_m,
                        const float* __restrict__ part_l, const float* __restrict__ qatt,
                        const float* __restrict__ q_v, float* __restrict__ out) {
  int idx = blockIdx.x * blockDim.x + threadIdx.x;  // one per float4
  int n = idx >> 7;
  int d4 = (idx & 127) * 4;
  float qa = qatt[n];
  float mm[8], M = -1e30f;
#pragma unroll
  for (int w = 0; w < 8; ++w) {
    mm[w] = part_m[(size_t)w * NQ + n];
    M = fmaxf(M, mm[w]);
  }
  float denom = __expf(qa * SCALE - M);  // the extra q_att column
  float4 r = {0.f, 0.f, 0.f, 0.f};
#pragma unroll
  for (int w = 0; w < 8; ++w) {
    float e = __expf(mm[w] - M);
    denom += part_l[(size_t)w * NQ + n] * e;
    float4 po = *(const float4*)(part_O + ((size_t)w * NQ + n) * DVC + d4);
    r.x += e * po.x; r.y += e * po.y; r.z += e * po.z; r.w += e * po.w;
  }
  float inv = 1.0f / denom;
  float4 qv = *(const float4*)(q_v + (size_t)n * DVC + d4);
  float4 o;
  o.x = qv.x * qa + r.x * inv;
  o.y = qv.y * qa + r.y * inv;
  o.z = qv.z * qa + r.z * inv;
  o.w = qv.w * qa + r.w * inv;
  *(float4*)(out + (size_t)n * DVC + d4) = o;
}

extern "C" void kernel_launch(void* const* d_in, const int* in_sizes, int n_in,
                              void* d_out, int out_size, void* d_ws, size_t ws_size,
                              hipStream_t stream) {
  const float* query = (const float*)d_in[0];
  const float* q_k = (const float*)d_in[1];
  const float* q_v = (const float*)d_in[2];
  const float* key = (const float*)d_in[3];
  const float* value = (const float*)d_in[4];
  float* out = (float*)d_out;

  char* ws = (char*)d_ws;
  unsigned short* Qb = (unsigned short*)(ws);                    // 4 MB
  unsigned short* Kb = (unsigned short*)(ws + (4u << 20));       // 4 MB
  unsigned short* Vt = (unsigned short*)(ws + (8u << 20));       // 4 MB
  float* qatt = (float*)(ws + (12u << 20));                      // 16 KB (pad to 64)
  float* part_m = (float*)(ws + (12u << 20) + (1u << 16));       // 128 KB
  float* part_l = (float*)(ws + (12u << 20) + (1u << 16) + (1u << 17));
  float* part_O = (float*)(ws + (12u << 20) + (1u << 16) + 2u * (1u << 17));  // 64 MB

  prep_q<<<dim3(1024), dim3(256), 0, stream>>>(query, q_k, Qb, qatt);
  prep_k<<<dim3(1024), dim3(256), 0, stream>>>(key, Kb);
  prep_vt<<<dim3(128, 16), dim3(256), 0, stream>>>(value, Vt);
  attn_partial<<<dim3(256), dim3(512), 0, stream>>>(Qb, Kb, Vt, part_O, part_m, part_l);
  combine<<<dim3(2048), dim3(256), 0, stream>>>(part_O, part_m, part_l, qatt, q_v, out);
}

// Round 2
// 237.945 us; speedup vs baseline: 1.0881x; 1.0881x over previous
//
#include <hip/hip_runtime.h>

#define NQ 4096
#define MK 4096
#define DKC 512
#define DVC 512
#define SCALE 0.044151079f  // 1/sqrt(513)
#define NCHUNK 16

typedef __attribute__((ext_vector_type(8))) short short8;
typedef __attribute__((ext_vector_type(4))) float f32x4;

__device__ __forceinline__ unsigned short f2bf(float x) {
  unsigned u = __float_as_uint(x);
  u += 0x7fffu + ((u >> 16) & 1u);
  return (unsigned short)(u >> 16);
}
__device__ __forceinline__ float bf2f(unsigned short h) {
  return __uint_as_float((unsigned)h << 16);
}

#define GLL16(g, l)                                                        \
  __builtin_amdgcn_global_load_lds(                                        \
      (const __attribute__((address_space(1))) unsigned int*)(g),          \
      (__attribute__((address_space(3))) unsigned int*)(l), 16, 0, 0)

// ---------------- prep: query -> bf16, q_att = rowdot(query, q_k) ----------------
__global__ void prep_q(const float* __restrict__ query, const float* __restrict__ q_k,
                       unsigned short* __restrict__ Qb, float* __restrict__ qatt) {
  int n = blockIdx.x * 4 + (threadIdx.x >> 6);
  int lane = threadIdx.x & 63;
  const float4* qr = (const float4*)(query + (size_t)n * DKC + lane * 8);
  const float4* kr = (const float4*)(q_k + (size_t)n * DKC + lane * 8);
  float4 a0 = qr[0], a1 = qr[1];
  float4 b0 = kr[0], b1 = kr[1];
  float dot = a0.x * b0.x + a0.y * b0.y + a0.z * b0.z + a0.w * b0.w +
              a1.x * b1.x + a1.y * b1.y + a1.z * b1.z + a1.w * b1.w;
  unsigned short h[8] = {f2bf(a0.x), f2bf(a0.y), f2bf(a0.z), f2bf(a0.w),
                         f2bf(a1.x), f2bf(a1.y), f2bf(a1.z), f2bf(a1.w)};
  *(short8*)(Qb + (size_t)n * DKC + lane * 8) = *(short8*)h;
#pragma unroll
  for (int off = 1; off < 64; off <<= 1) dot += __shfl_xor(dot, off, 64);
  if (lane == 0) qatt[n] = dot;
}

// ---------------- prep: key -> bf16 ----------------
__global__ void prep_k(const float* __restrict__ key, unsigned short* __restrict__ Kb) {
  int i = blockIdx.x * blockDim.x + threadIdx.x;  // one per 8 elements
  const float4* src = (const float4*)key + (size_t)i * 2;
  float4 a0 = src[0], a1 = src[1];
  unsigned short h[8] = {f2bf(a0.x), f2bf(a0.y), f2bf(a0.z), f2bf(a0.w),
                         f2bf(a1.x), f2bf(a1.y), f2bf(a1.z), f2bf(a1.w)};
  *(short8*)(Kb + (size_t)i * 8) = *(short8*)h;
}

// ---------------- prep: value -> bf16 transposed Vt[d][m] ----------------
__global__ void prep_vt(const float* __restrict__ value, unsigned short* __restrict__ Vt) {
  __shared__ float t[32][33];
  int tx = threadIdx.x & 31, ty = threadIdx.x >> 5;  // 32x8
  int m0 = blockIdx.x * 32;
  int d0 = blockIdx.y * 32;
#pragma unroll
  for (int i = 0; i < 4; ++i)
    t[ty + i * 8][tx] = value[(size_t)(m0 + ty + i * 8) * DVC + d0 + tx];
  __syncthreads();
#pragma unroll
  for (int i = 0; i < 4; ++i)
    Vt[(size_t)(d0 + ty + i * 8) * MK + m0 + tx] = f2bf(t[tx][ty + i * 8]);
}

// ---------------- attention partials: grid = 32 qb x 8 mc ----------------
// LDS: double-buffered K (2x32KB) + V (2x32KB) + per-wave P (8KB) = 136 KB
__global__ __launch_bounds__(512, 2) void attn_partial(
    const unsigned short* __restrict__ Qb, const unsigned short* __restrict__ Kb,
    const unsigned short* __restrict__ Vt, unsigned short* __restrict__ part_O,
    float* __restrict__ part_m, float* __restrict__ part_l) {
  __shared__ __align__(16) char lds[139264];
  // layout: kbuf0 @0, kbuf1 @32768, vbuf0 @65536, vbuf1 @98304, p_lds @131072

  const int tid = threadIdx.x;
  const int wid = tid >> 6;
  const int lane = tid & 63;
  const int lr = lane & 15;
  const int lh = lane >> 4;

  const int qb = blockIdx.x >> 3;
  const int mc = blockIdx.x & 7;
  const int qrow0 = qb * 128 + wid * 16;

  unsigned short* p_lds = (unsigned short*)(lds + 131072) + wid * 512;  // [16][32]

  // Q fragments: A[row=lr][k = kk*32 + lh*8 + j]
  short8 qf[16];
  {
    const short8* qp = (const short8*)(Qb + (size_t)(qrow0 + lr) * DKC);
#pragma unroll
    for (int kk = 0; kk < 16; ++kk) qf[kk] = qp[kk * 4 + lh];
  }

  float m[4] = {-1e30f, -1e30f, -1e30f, -1e30f};
  float lsum[4] = {0.f, 0.f, 0.f, 0.f};
  f32x4 acc[32];
#pragma unroll
  for (int i = 0; i < 32; ++i) acc[i] = (f32x4){0.f, 0.f, 0.f, 0.f};

  const char* kgbase = (const char*)Kb + (size_t)mc * 512 * DKC * 2;
  const char* vgbase = (const char*)Vt;

  // stage-issue for chunk c into buffer b (8 global_load_lds per thread, no wait)
  auto stage_issue = [&](int c, int b) {
    const char* kg = kgbase + (size_t)c * 32 * DKC * 2;
    const size_t vcol = (size_t)(mc * 512 + c * 32) * 2;
    char* kl = lds + b * 32768;
    char* vl = lds + 65536 + b * 32768;
#pragma unroll
    for (int s = 0; s < 4; ++s) {
      int obase = s * 8192 + wid * 1024;  // wave-uniform LDS base; HW adds lane*16
      int o = obase + lane * 16;
      int srck = o ^ (((o >> 10) & 7) << 4);
      GLL16(kg + srck, kl + obase);
      int lv = o ^ (((o >> 7) & 3) << 4);
      int d = lv >> 6, ib = lv & 63;
      GLL16(vgbase + (size_t)d * (MK * 2) + vcol + ib, vl + obase);
    }
  };

  stage_issue(0, 0);  // prologue: 8 outstanding

  for (int c = 0; c < NCHUNK; ++c) {
    const int cur = c & 1;
    const char* kl = lds + cur * 32768;
    const char* vl = lds + 65536 + cur * 32768;

    if (c + 1 < NCHUNK) {
      stage_issue(c + 1, cur ^ 1);  // 8 more in flight under this chunk's compute
      asm volatile("s_waitcnt vmcnt(8)" ::: "memory");  // chunk c's loads landed
    } else {
      asm volatile("s_waitcnt vmcnt(0)" ::: "memory");
    }
    __builtin_amdgcn_s_barrier();  // all waves staged buf[cur]
    asm volatile("" ::: "memory");

    // ---- S = Q * Kc^T : two 16x16 tiles over K=512 ----
    f32x4 sa0 = {0.f, 0.f, 0.f, 0.f}, sa1 = {0.f, 0.f, 0.f, 0.f};
#pragma unroll
    for (int kk = 0; kk < 16; ++kk) {
      int b0 = (lr * 1024 + kk * 64 + lh * 16) ^ ((lr & 7) << 4);
      int b1 = ((16 + lr) * 1024 + kk * 64 + lh * 16) ^ ((lr & 7) << 4);
      short8 kf0 = *(const short8*)(kl + b0);
      short8 kf1 = *(const short8*)(kl + b1);
      sa0 = __builtin_amdgcn_mfma_f32_16x16x32_bf16(qf[kk], kf0, sa0, 0, 0, 0);
      sa1 = __builtin_amdgcn_mfma_f32_16x16x32_bf16(qf[kk], kf1, sa1, 0, 0, 0);
    }

    // ---- online softmax (rows = lh*4+r, keys = lr and 16+lr) ----
    float sv0[4], sv1[4], rmax[4];
#pragma unroll
    for (int r = 0; r < 4; ++r) {
      sv0[r] = sa0[r] * SCALE;
      sv1[r] = sa1[r] * SCALE;
      rmax[r] = fmaxf(sv0[r], sv1[r]);
    }
#pragma unroll
    for (int off = 1; off < 16; off <<= 1)
#pragma unroll
      for (int r = 0; r < 4; ++r) rmax[r] = fmaxf(rmax[r], __shfl_xor(rmax[r], off, 64));
    float alpha[4];
    bool need = false;
#pragma unroll
    for (int r = 0; r < 4; ++r) {
      float nm = fmaxf(m[r], rmax[r]);
      alpha[r] = __expf(m[r] - nm);
      m[r] = nm;
      need = need || (alpha[r] != 1.0f);
    }
    if (__any(need)) {
#pragma unroll
      for (int dt = 0; dt < 32; ++dt)
#pragma unroll
        for (int r = 0; r < 4; ++r) acc[dt][r] *= alpha[r];
#pragma unroll
      for (int r = 0; r < 4; ++r) lsum[r] *= alpha[r];
    }
#pragma unroll
    for (int r = 0; r < 4; ++r) {
      float p0 = __expf(sv0[r] - m[r]);
      float p1 = __expf(sv1[r] - m[r]);
      lsum[r] += p0 + p1;
      p_lds[(lh * 4 + r) * 32 + lr] = f2bf(p0);
      p_lds[(lh * 4 + r) * 32 + 16 + lr] = f2bf(p1);
    }
    // A-frag of P: row=lr, k = lh*8+j (same-wave LDS; compiler orders via lgkmcnt)
    short8 pf = *(const short8*)(p_lds + lr * 32 + lh * 8);

    // ---- O += P * Vc over 32 d-tiles ----
#pragma unroll
    for (int dt = 0; dt < 32; ++dt) {
      int d = dt * 16 + lr;
      int b = (d * 64 + lh * 16) ^ (((d >> 1) & 3) << 4);
      short8 vf = *(const short8*)(vl + b);
      acc[dt] = __builtin_amdgcn_mfma_f32_16x16x32_bf16(pf, vf, acc[dt], 0, 0, 0);
    }

    asm volatile("" ::: "memory");
    __builtin_amdgcn_s_barrier();  // all waves done reading buf[cur] before overwrite
    asm volatile("" ::: "memory");
  }

  // ---- finalize: reduce lsum across the 16 key-lanes ----
#pragma unroll
  for (int off = 1; off < 16; off <<= 1)
#pragma unroll
    for (int r = 0; r < 4; ++r) lsum[r] += __shfl_xor(lsum[r], off, 64);

  if (lr == 0) {
#pragma unroll
    for (int r = 0; r < 4; ++r) {
      int row = qrow0 + lh * 4 + r;
      part_m[(size_t)mc * NQ + row] = m[r];
      part_l[(size_t)mc * NQ + row] = lsum[r];
    }
  }
#pragma unroll
  for (int dt = 0; dt < 32; ++dt)
#pragma unroll
    for (int r = 0; r < 4; ++r) {
      int row = qrow0 + lh * 4 + r;
      part_O[((size_t)mc * NQ + row) * DVC + dt * 16 + lr] = f2bf(acc[dt][r]);
    }
}

// ---------------- combine partials + epilogue ----------------
__global__ void combine(const unsigned short* __restrict__ part_O,
                        const float* __restrict__ part_m, const float* __restrict__ part_l,
                        const float* __restrict__ qatt, const float* __restrict__ q_v,
                        float* __restrict__ out) {
  int idx = blockIdx.x * blockDim.x + threadIdx.x;  // one per 8 output elems
  int n = idx >> 6;
  int d8 = (idx & 63) * 8;
  float qa = qatt[n];
  float mm[8], M = -1e30f;
#pragma unroll
  for (int w = 0; w < 8; ++w) {
    mm[w] = part_m[(size_t)w * NQ + n];
    M = fmaxf(M, mm[w]);
  }
  float denom = __expf(qa * SCALE - M);  // the extra q_att column
  float r[8] = {0.f, 0.f, 0.f, 0.f, 0.f, 0.f, 0.f, 0.f};
#pragma unroll
  for (int w = 0; w < 8; ++w) {
    float e = __expf(mm[w] - M);
    denom += part_l[(size_t)w * NQ + n] * e;
    short8 po = *(const short8*)(part_O + ((size_t)w * NQ + n) * DVC + d8);
#pragma unroll
    for (int j = 0; j < 8; ++j) r[j] += e * bf2f((unsigned short)po[j]);
  }
  float inv = 1.0f / denom;
  const float4* qv = (const float4*)(q_v + (size_t)n * DVC + d8);
  float4 qv0 = qv[0], qv1 = qv[1];
  float4 o0, o1;
  o0.x = qv0.x * qa + r[0] * inv;
  o0.y = qv0.y * qa + r[1] * inv;
  o0.z = qv0.z * qa + r[2] * inv;
  o0.w = qv0.w * qa + r[3] * inv;
  o1.x = qv1.x * qa + r[4] * inv;
  o1.y = qv1.y * qa + r[5] * inv;
  o1.z = qv1.z * qa + r[6] * inv;
  o1.w = qv1.w * qa + r[7] * inv;
  float4* op = (float4*)(out + (size_t)n * DVC + d8);
  op[0] = o0;
  op[1] = o1;
}

extern "C" void kernel_launch(void* const* d_in, const int* in_sizes, int n_in,
                              void* d_out, int out_size, void* d_ws, size_t ws_size,
                              hipStream_t stream) {
  const float* query = (const float*)d_in[0];
  const float* q_k = (const float*)d_in[1];
  const float* q_v = (const float*)d_in[2];
  const float* key = (const float*)d_in[3];
  const float* value = (const float*)d_in[4];
  float* out = (float*)d_out;

  char* ws = (char*)d_ws;
  unsigned short* Qb = (unsigned short*)(ws);                    // 4 MB
  unsigned short* Kb = (unsigned short*)(ws + (4u << 20));       // 4 MB
  unsigned short* Vt = (unsigned short*)(ws + (8u << 20));       // 4 MB
  float* qatt = (float*)(ws + (12u << 20));                      // 16 KB (pad to 64)
  float* part_m = (float*)(ws + (12u << 20) + (1u << 16));       // 128 KB
  float* part_l = (float*)(ws + (12u << 20) + (1u << 16) + (1u << 17));
  unsigned short* part_O =
      (unsigned short*)(ws + (12u << 20) + (1u << 16) + 2u * (1u << 17));  // 32 MB bf16

  prep_q<<<dim3(1024), dim3(256), 0, stream>>>(query, q_k, Qb, qatt);
  prep_k<<<dim3(1024), dim3(256), 0, stream>>>(key, Kb);
  prep_vt<<<dim3(128, 16), dim3(256), 0, stream>>>(value, Vt);
  attn_partial<<<dim3(256), dim3(512), 0, stream>>>(Qb, Kb, Vt, part_O, part_m, part_l);
  combine<<<dim3(1024), dim3(256), 0, stream>>>(part_O, part_m, part_l, qatt, q_v, out);
}

// Round 3
// 104.588 us; speedup vs baseline: 2.4755x; 2.2751x over previous
//
#include <hip/hip_runtime.h>

#define NQ 4096
#define MK 4096
#define DKC 512
#define DVC 512
#define SCALE 0.044151079f  // 1/sqrt(513)

typedef __attribute__((ext_vector_type(8))) short short8;
typedef __attribute__((ext_vector_type(4))) float f32x4;

__device__ __forceinline__ unsigned short f2bf(float x) {
  unsigned u = __float_as_uint(x);
  u += 0x7fffu + ((u >> 16) & 1u);
  return (unsigned short)(u >> 16);
}
__device__ __forceinline__ float bf2f(unsigned short h) {
  return __uint_as_float((unsigned)h << 16);
}

#define GLL16(g, l)                                                        \
  __builtin_amdgcn_global_load_lds(                                        \
      (const __attribute__((address_space(1))) unsigned int*)(g),          \
      (__attribute__((address_space(3))) unsigned int*)(l), 16, 0, 0)

// ---------------- prep: query -> bf16, q_att = rowdot(query, q_k) ----------------
__global__ void prep_q(const float* __restrict__ query, const float* __restrict__ q_k,
                       unsigned short* __restrict__ Qb, float* __restrict__ qatt) {
  int n = blockIdx.x * 4 + (threadIdx.x >> 6);
  int lane = threadIdx.x & 63;
  const float4* qr = (const float4*)(query + (size_t)n * DKC + lane * 8);
  const float4* kr = (const float4*)(q_k + (size_t)n * DKC + lane * 8);
  float4 a0 = qr[0], a1 = qr[1];
  float4 b0 = kr[0], b1 = kr[1];
  float dot = a0.x * b0.x + a0.y * b0.y + a0.z * b0.z + a0.w * b0.w +
              a1.x * b1.x + a1.y * b1.y + a1.z * b1.z + a1.w * b1.w;
  unsigned short h[8] = {f2bf(a0.x), f2bf(a0.y), f2bf(a0.z), f2bf(a0.w),
                         f2bf(a1.x), f2bf(a1.y), f2bf(a1.z), f2bf(a1.w)};
  *(short8*)(Qb + (size_t)n * DKC + lane * 8) = *(short8*)h;
#pragma unroll
  for (int off = 1; off < 64; off <<= 1) dot += __shfl_xor(dot, off, 64);
  if (lane == 0) qatt[n] = dot;
}

// ---------------- prep: key -> bf16 ----------------
__global__ void prep_k(const float* __restrict__ key, unsigned short* __restrict__ Kb) {
  int i = blockIdx.x * blockDim.x + threadIdx.x;  // one per 8 elements
  const float4* src = (const float4*)key + (size_t)i * 2;
  float4 a0 = src[0], a1 = src[1];
  unsigned short h[8] = {f2bf(a0.x), f2bf(a0.y), f2bf(a0.z), f2bf(a0.w),
                         f2bf(a1.x), f2bf(a1.y), f2bf(a1.z), f2bf(a1.w)};
  *(short8*)(Kb + (size_t)i * 8) = *(short8*)h;
}

// ---------------- prep: value -> bf16 transposed Vt[d][m] ----------------
__global__ void prep_vt(const float* __restrict__ value, unsigned short* __restrict__ Vt) {
  __shared__ float t[32][33];
  int tx = threadIdx.x & 31, ty = threadIdx.x >> 5;  // 32x8
  int m0 = blockIdx.x * 32;
  int d0 = blockIdx.y * 32;
#pragma unroll
  for (int i = 0; i < 4; ++i)
    t[ty + i * 8][tx] = value[(size_t)(m0 + ty + i * 8) * DVC + d0 + tx];
  __syncthreads();
#pragma unroll
  for (int i = 0; i < 4; ++i)
    Vt[(size_t)(d0 + ty + i * 8) * MK + m0 + tx] = f2bf(t[tx][ty + i * 8]);
}

// ---------------- gemm_s: S[4096][4096] bf16 = Qb * Kb^T (K=512) ----------------
// m97 structure: 128x128 tile, BK=64, 4 waves (2x2), global_load_lds w=16,
// XOR-swizzled LDS reads, 2 barriers/K-step. Epilogue: LDS bounce -> coalesced stores.
__global__ __launch_bounds__(256, 3) void gemm_s(const unsigned short* __restrict__ Qb,
                                                 const unsigned short* __restrict__ Kb,
                                                 unsigned short* __restrict__ S) {
  __shared__ __align__(16) char lds[32768];  // A@0 (16K), B@16K (16K); epilogue reuses all
  const int tid = threadIdx.x;
  const int wid = tid >> 6, lane = tid & 63, lr = lane & 15, lh = lane >> 4;
  const int wm = wid >> 1, wn = wid & 1;

  int bid = blockIdx.x;                    // 1024 WGs, bijective XCD swizzle (1024%8==0)
  int swz = (bid & 7) * 128 + (bid >> 3);
  const int tm = swz >> 5, tn = swz & 31;
  const size_t m0 = (size_t)tm * 128, n0 = (size_t)tn * 128;

  f32x4 acc[4][4];
#pragma unroll
  for (int i = 0; i < 4; ++i)
#pragma unroll
    for (int j = 0; j < 4; ++j) acc[i][j] = (f32x4){0.f, 0.f, 0.f, 0.f};

  const char* abase = (const char*)Qb + m0 * 1024;  // row stride 1024 B
  const char* bbase = (const char*)Kb + n0 * 1024;

  for (int ks = 0; ks < 8; ++ks) {
    const int kb = ks * 128;  // 64 elems = 128 B per K-step
    {
      char* al = lds;
      char* bl = lds + 16384;
#pragma unroll
      for (int s = 0; s < 4; ++s) {
        int obase = wid * 4096 + s * 1024;  // wave-uniform LDS base; HW adds lane*16
        int o = obase + lane * 16;
        int row = o >> 7;                                 // 128 B per LDS row
        int colg = ((o >> 4) & 7) ^ (row & 7);            // inverse-swizzled source granule
        GLL16(abase + (size_t)row * 1024 + kb + colg * 16, al + obase);
        GLL16(bbase + (size_t)row * 1024 + kb + colg * 16, bl + obase);
      }
    }
    __syncthreads();
#pragma unroll
    for (int kk = 0; kk < 2; ++kk) {
      short8 af[4], bf[4];
#pragma unroll
      for (int i = 0; i < 4; ++i) {
        int ar = wm * 64 + i * 16 + lr;
        af[i] = *(const short8*)(lds + ar * 128 + ((((kk << 2) + lh) ^ (lr & 7)) << 4));
        int br = wn * 64 + i * 16 + lr;
        bf[i] = *(const short8*)(lds + 16384 + br * 128 + ((((kk << 2) + lh) ^ (lr & 7)) << 4));
      }
#pragma unroll
      for (int i = 0; i < 4; ++i)
#pragma unroll
        for (int j = 0; j < 4; ++j)
          acc[i][j] = __builtin_amdgcn_mfma_f32_16x16x32_bf16(af[i], bf[j], acc[i][j], 0, 0, 0);
    }
    __syncthreads();
  }

  // epilogue: bf16 bounce through LDS [128][128], then fully-coalesced 16B stores
  unsigned short* sl = (unsigned short*)lds;
#pragma unroll
  for (int i = 0; i < 4; ++i)
#pragma unroll
    for (int j = 0; j < 4; ++j)
#pragma unroll
      for (int r = 0; r < 4; ++r) {
        int m = wm * 64 + i * 16 + lh * 4 + r;
        int n = wn * 64 + j * 16 + lr;
        sl[m * 128 + n] = f2bf(acc[i][j][r]);
      }
  __syncthreads();
#pragma unroll
  for (int i = 0; i < 8; ++i) {
    int o = i * 4096 + tid * 16;
    int row = o >> 8, colb = o & 255;  // 256 B per bf16 tile row
    *(uint4*)((char*)S + (m0 + row) * 8192 + n0 * 2 + colb) = *(const uint4*)((const char*)sl + o);
  }
}

// ---------------- softmax_rows: in-place S -> P' = softmax_row/denom (bf16) ----------------
__global__ __launch_bounds__(256) void softmax_rows(unsigned short* __restrict__ S,
                                                    const float* __restrict__ qatt) {
  __shared__ float red[8];
  const int n = blockIdx.x;
  const int t = threadIdx.x;
  const int wv = t >> 6, lane = t & 63;
  unsigned short* row = S + (size_t)n * MK;
  short8 v0 = *(const short8*)(row + t * 16);
  short8 v1 = *(const short8*)(row + t * 16 + 8);
  float f[16];
#pragma unroll
  for (int j = 0; j < 8; ++j) {
    f[j] = bf2f((unsigned short)v0[j]) * SCALE;
    f[8 + j] = bf2f((unsigned short)v1[j]) * SCALE;
  }
  float mx = f[0];
#pragma unroll
  for (int j = 1; j < 16; ++j) mx = fmaxf(mx, f[j]);
#pragma unroll
  for (int off = 1; off < 64; off <<= 1) mx = fmaxf(mx, __shfl_xor(mx, off, 64));
  if (lane == 0) red[wv] = mx;
  __syncthreads();
  mx = fmaxf(fmaxf(red[0], red[1]), fmaxf(red[2], red[3]));
  float qa = qatt[n] * SCALE;
  mx = fmaxf(mx, qa);
  float e[16], s = 0.f;
#pragma unroll
  for (int j = 0; j < 16; ++j) {
    e[j] = __expf(f[j] - mx);
    s += e[j];
  }
#pragma unroll
  for (int off = 1; off < 64; off <<= 1) s += __shfl_xor(s, off, 64);
  if (lane == 0) red[4 + wv] = s;
  __syncthreads();
  float denom = red[4] + red[5] + red[6] + red[7] + __expf(qa - mx);
  float inv = 1.0f / denom;
  unsigned short h[16];
#pragma unroll
  for (int j = 0; j < 16; ++j) h[j] = f2bf(e[j] * inv);
  *(short8*)(row + t * 16) = *(short8*)h;
  *(short8*)(row + t * 16 + 8) = *(short8*)(h + 8);
}

// ---------------- gemm_o: out[4096][512] = q_v*q_att + P' * V  (K=4096) ----------------
// 128x64 tile -> 256 WGs; fused epilogue.
__global__ __launch_bounds__(256, 2) void gemm_o(const unsigned short* __restrict__ P,
                                                 const unsigned short* __restrict__ Vt,
                                                 const float* __restrict__ qatt,
                                                 const float* __restrict__ q_v,
                                                 float* __restrict__ out) {
  __shared__ __align__(16) char lds[32768];  // staging A@0 (16K) B@16K (8K); epilogue f32 32K
  const int tid = threadIdx.x;
  const int wid = tid >> 6, lane = tid & 63, lr = lane & 15, lh = lane >> 4;
  const int wm = wid >> 1, wn = wid & 1;

  int bid = blockIdx.x;                   // 256 WGs, 256%8==0
  int swz = (bid & 7) * 32 + (bid >> 3);
  const int tm = swz >> 3, tn = swz & 7;  // 32 x 8
  const size_t m0 = (size_t)tm * 128, n0 = (size_t)tn * 64;

  f32x4 acc[4][2];
#pragma unroll
  for (int i = 0; i < 4; ++i)
#pragma unroll
    for (int j = 0; j < 2; ++j) acc[i][j] = (f32x4){0.f, 0.f, 0.f, 0.f};

  const char* abase = (const char*)P + m0 * 8192;   // P row stride 8192 B
  const char* bbase = (const char*)Vt + n0 * 8192;  // Vt row stride 8192 B

  for (int ks = 0; ks < 64; ++ks) {
    const int kb = ks * 128;
    {
#pragma unroll
      for (int s = 0; s < 4; ++s) {
        int obase = wid * 4096 + s * 1024;
        int o = obase + lane * 16;
        int row = o >> 7;
        int colg = ((o >> 4) & 7) ^ (row & 7);
        GLL16(abase + (size_t)row * 8192 + kb + colg * 16, lds + obase);
      }
#pragma unroll
      for (int s = 0; s < 2; ++s) {
        int obase = wid * 2048 + s * 1024;
        int o = obase + lane * 16;
        int row = o >> 7;
        int colg = ((o >> 4) & 7) ^ (row & 7);
        GLL16(bbase + (size_t)row * 8192 + kb + colg * 16, lds + 16384 + obase);
      }
    }
    __syncthreads();
#pragma unroll
    for (int kk = 0; kk < 2; ++kk) {
      short8 af[4], bf[2];
#pragma unroll
      for (int i = 0; i < 4; ++i) {
        int ar = wm * 64 + i * 16 + lr;
        af[i] = *(const short8*)(lds + ar * 128 + ((((kk << 2) + lh) ^ (lr & 7)) << 4));
      }
#pragma unroll
      for (int j = 0; j < 2; ++j) {
        int br = wn * 32 + j * 16 + lr;
        bf[j] = *(const short8*)(lds + 16384 + br * 128 + ((((kk << 2) + lh) ^ (lr & 7)) << 4));
      }
#pragma unroll
      for (int i = 0; i < 4; ++i)
#pragma unroll
        for (int j = 0; j < 2; ++j)
          acc[i][j] = __builtin_amdgcn_mfma_f32_16x16x32_bf16(af[i], bf[j], acc[i][j], 0, 0, 0);
    }
    __syncthreads();
  }

  // epilogue: f32 bounce [128][64] + fused  out = q_v*qa + acc
  float* fl = (float*)lds;
#pragma unroll
  for (int i = 0; i < 4; ++i)
#pragma unroll
    for (int j = 0; j < 2; ++j)
#pragma unroll
      for (int r = 0; r < 4; ++r) {
        int m = wm * 64 + i * 16 + lh * 4 + r;
        int n = wn * 32 + j * 16 + lr;
        fl[m * 64 + n] = acc[i][j][r];
      }
  __syncthreads();
#pragma unroll
  for (int i = 0; i < 8; ++i) {
    int o = i * 4096 + tid * 16;
    int row = o >> 8, colb = o & 255;  // 256 B per f32 tile row (64 floats)
    size_t gq = m0 + row;
    float qa = qatt[gq];
    float4 qv = *(const float4*)((const char*)q_v + gq * 2048 + n0 * 4 + colb);
    float4 a = *(const float4*)((const char*)fl + o);
    float4 r4 = {qv.x * qa + a.x, qv.y * qa + a.y, qv.z * qa + a.z, qv.w * qa + a.w};
    *(float4*)((char*)out + gq * 2048 + n0 * 4 + colb) = r4;
  }
}

extern "C" void kernel_launch(void* const* d_in, const int* in_sizes, int n_in,
                              void* d_out, int out_size, void* d_ws, size_t ws_size,
                              hipStream_t stream) {
  const float* query = (const float*)d_in[0];
  const float* q_k = (const float*)d_in[1];
  const float* q_v = (const float*)d_in[2];
  const float* key = (const float*)d_in[3];
  const float* value = (const float*)d_in[4];
  float* out = (float*)d_out;

  char* ws = (char*)d_ws;
  unsigned short* Qb = (unsigned short*)(ws);                 // 4 MB
  unsigned short* Kb = (unsigned short*)(ws + (4u << 20));    // 4 MB
  unsigned short* Vt = (unsigned short*)(ws + (8u << 20));    // 4 MB
  unsigned short* S = (unsigned short*)(ws + (12u << 20));    // 32 MB (S, then P' in-place)
  float* qatt = (float*)(ws + (44u << 20));                   // 16 KB

  prep_q<<<dim3(1024), dim3(256), 0, stream>>>(query, q_k, Qb, qatt);
  prep_k<<<dim3(1024), dim3(256), 0, stream>>>(key, Kb);
  prep_vt<<<dim3(128, 16), dim3(256), 0, stream>>>(value, Vt);
  gemm_s<<<dim3(1024), dim3(256), 0, stream>>>(Qb, Kb, S);
  softmax_rows<<<dim3(4096), dim3(256), 0, stream>>>(S, qatt);
  gemm_o<<<dim3(256), dim3(256), 0, stream>>>(S, Vt, qatt, q_v, out);
}

// Round 5
// 85.369 us; speedup vs baseline: 3.0329x; 1.2251x over previous
//
#include <hip/hip_runtime.h>

#define NQ 4096
#define MK 4096
#define DKC 512
#define DVC 512
#define SCALE 0.044151079f  // 1/sqrt(513)

typedef __attribute__((ext_vector_type(8))) short short8;
typedef __attribute__((ext_vector_type(4))) float f32x4;

__device__ __forceinline__ unsigned short f2bf(float x) {
  unsigned u = __float_as_uint(x);
  u += 0x7fffu + ((u >> 16) & 1u);
  return (unsigned short)(u >> 16);
}
__device__ __forceinline__ float bf2f(unsigned short h) {
  return __uint_as_float((unsigned)h << 16);
}

#define GLL16(g, l)                                                        \
  __builtin_amdgcn_global_load_lds(                                        \
      (const __attribute__((address_space(1))) unsigned int*)(g),          \
      (__attribute__((address_space(3))) unsigned int*)(l), 16, 0, 0)

// ---------------- prep: query -> bf16, q_att = rowdot(query, q_k) ----------------
__global__ void prep_q(const float* __restrict__ query, const float* __restrict__ q_k,
                       unsigned short* __restrict__ Qb, float* __restrict__ qatt) {
  int n = blockIdx.x * 4 + (threadIdx.x >> 6);
  int lane = threadIdx.x & 63;
  const float4* qr = (const float4*)(query + (size_t)n * DKC + lane * 8);
  const float4* kr = (const float4*)(q_k + (size_t)n * DKC + lane * 8);
  float4 a0 = qr[0], a1 = qr[1];
  float4 b0 = kr[0], b1 = kr[1];
  float dot = a0.x * b0.x + a0.y * b0.y + a0.z * b0.z + a0.w * b0.w +
              a1.x * b1.x + a1.y * b1.y + a1.z * b1.z + a1.w * b1.w;
  unsigned short h[8] = {f2bf(a0.x), f2bf(a0.y), f2bf(a0.z), f2bf(a0.w),
                         f2bf(a1.x), f2bf(a1.y), f2bf(a1.z), f2bf(a1.w)};
  *(short8*)(Qb + (size_t)n * DKC + lane * 8) = *(short8*)h;
#pragma unroll
  for (int off = 1; off < 64; off <<= 1) dot += __shfl_xor(dot, off, 64);
  if (lane == 0) qatt[n] = dot;
}

// ---------------- prep: key -> bf16 ----------------
__global__ void prep_k(const float* __restrict__ key, unsigned short* __restrict__ Kb) {
  int i = blockIdx.x * blockDim.x + threadIdx.x;  // one per 8 elements
  const float4* src = (const float4*)key + (size_t)i * 2;
  float4 a0 = src[0], a1 = src[1];
  unsigned short h[8] = {f2bf(a0.x), f2bf(a0.y), f2bf(a0.z), f2bf(a0.w),
                         f2bf(a1.x), f2bf(a1.y), f2bf(a1.z), f2bf(a1.w)};
  *(short8*)(Kb + (size_t)i * 8) = *(short8*)h;
}

// ---------------- prep: value -> bf16 transposed Vt[d][m] ----------------
__global__ void prep_vt(const float* __restrict__ value, unsigned short* __restrict__ Vt) {
  __shared__ float t[32][33];
  int tx = threadIdx.x & 31, ty = threadIdx.x >> 5;  // 32x8
  int m0 = blockIdx.x * 32;
  int d0 = blockIdx.y * 32;
#pragma unroll
  for (int i = 0; i < 4; ++i)
    t[ty + i * 8][tx] = value[(size_t)(m0 + ty + i * 8) * DVC + d0 + tx];
  __syncthreads();
#pragma unroll
  for (int i = 0; i < 4; ++i)
    Vt[(size_t)(d0 + ty + i * 8) * MK + m0 + tx] = f2bf(t[tx][ty + i * 8]);
}

// ---------------- gemm_s: S[4096][4096] bf16 = Qb * Kb^T (K=512) ----------------
__global__ __launch_bounds__(256, 3) void gemm_s(const unsigned short* __restrict__ Qb,
                                                 const unsigned short* __restrict__ Kb,
                                                 unsigned short* __restrict__ S) {
  __shared__ __align__(16) char lds[32768];  // A@0 (16K), B@16K (16K); epilogue reuses all
  const int tid = threadIdx.x;
  const int wid = tid >> 6, lane = tid & 63, lr = lane & 15, lh = lane >> 4;
  const int wm = wid >> 1, wn = wid & 1;

  int bid = blockIdx.x;                    // 1024 WGs, bijective XCD swizzle (1024%8==0)
  int swz = (bid & 7) * 128 + (bid >> 3);
  const int tm = swz >> 5, tn = swz & 31;
  const size_t m0 = (size_t)tm * 128, n0 = (size_t)tn * 128;

  f32x4 acc[4][4];
#pragma unroll
  for (int i = 0; i < 4; ++i)
#pragma unroll
    for (int j = 0; j < 4; ++j) acc[i][j] = (f32x4){0.f, 0.f, 0.f, 0.f};

  const char* abase = (const char*)Qb + m0 * 1024;  // row stride 1024 B
  const char* bbase = (const char*)Kb + n0 * 1024;

  for (int ks = 0; ks < 8; ++ks) {
    const int kb = ks * 128;  // 64 elems = 128 B per K-step
    {
      char* al = lds;
      char* bl = lds + 16384;
#pragma unroll
      for (int s = 0; s < 4; ++s) {
        int obase = wid * 4096 + s * 1024;  // wave-uniform LDS base; HW adds lane*16
        int o = obase + lane * 16;
        int row = o >> 7;                                 // 128 B per LDS row
        int colg = ((o >> 4) & 7) ^ (row & 7);            // inverse-swizzled source granule
        GLL16(abase + (size_t)row * 1024 + kb + colg * 16, al + obase);
        GLL16(bbase + (size_t)row * 1024 + kb + colg * 16, bl + obase);
      }
    }
    __syncthreads();
#pragma unroll
    for (int kk = 0; kk < 2; ++kk) {
      short8 af[4], bf[4];
#pragma unroll
      for (int i = 0; i < 4; ++i) {
        int ar = wm * 64 + i * 16 + lr;
        af[i] = *(const short8*)(lds + ar * 128 + ((((kk << 2) + lh) ^ (lr & 7)) << 4));
        int br = wn * 64 + i * 16 + lr;
        bf[i] = *(const short8*)(lds + 16384 + br * 128 + ((((kk << 2) + lh) ^ (lr & 7)) << 4));
      }
#pragma unroll
      for (int i = 0; i < 4; ++i)
#pragma unroll
        for (int j = 0; j < 4; ++j)
          acc[i][j] = __builtin_amdgcn_mfma_f32_16x16x32_bf16(af[i], bf[j], acc[i][j], 0, 0, 0);
    }
    __syncthreads();
  }

  // epilogue: bf16 bounce through LDS [128][128], then fully-coalesced 16B stores
  unsigned short* sl = (unsigned short*)lds;
#pragma unroll
  for (int i = 0; i < 4; ++i)
#pragma unroll
    for (int j = 0; j < 4; ++j)
#pragma unroll
      for (int r = 0; r < 4; ++r) {
        int m = wm * 64 + i * 16 + lh * 4 + r;
        int n = wn * 64 + j * 16 + lr;
        sl[m * 128 + n] = f2bf(acc[i][j][r]);
      }
  __syncthreads();
#pragma unroll
  for (int i = 0; i < 8; ++i) {
    int o = i * 4096 + tid * 16;
    int row = o >> 8, colb = o & 255;  // 256 B per bf16 tile row
    *(uint4*)((char*)S + (m0 + row) * 8192 + n0 * 2 + colb) = *(const uint4*)((const char*)sl + o);
  }
}

// ---------------- softmax_rows: in-place S -> P' = softmax_row/denom (bf16) ----------------
__global__ __launch_bounds__(256) void softmax_rows(unsigned short* __restrict__ S,
                                                    const float* __restrict__ qatt) {
  __shared__ float red[8];
  const int n = blockIdx.x;
  const int t = threadIdx.x;
  const int wv = t >> 6, lane = t & 63;
  unsigned short* row = S + (size_t)n * MK;
  short8 v0 = *(const short8*)(row + t * 16);
  short8 v1 = *(const short8*)(row + t * 16 + 8);
  float f[16];
#pragma unroll
  for (int j = 0; j < 8; ++j) {
    f[j] = bf2f((unsigned short)v0[j]) * SCALE;
    f[8 + j] = bf2f((unsigned short)v1[j]) * SCALE;
  }
  float mx = f[0];
#pragma unroll
  for (int j = 1; j < 16; ++j) mx = fmaxf(mx, f[j]);
#pragma unroll
  for (int off = 1; off < 64; off <<= 1) mx = fmaxf(mx, __shfl_xor(mx, off, 64));
  if (lane == 0) red[wv] = mx;
  __syncthreads();
  mx = fmaxf(fmaxf(red[0], red[1]), fmaxf(red[2], red[3]));
  float qa = qatt[n] * SCALE;
  mx = fmaxf(mx, qa);
  float e[16], s = 0.f;
#pragma unroll
  for (int j = 0; j < 16; ++j) {
    e[j] = __expf(f[j] - mx);
    s += e[j];
  }
#pragma unroll
  for (int off = 1; off < 64; off <<= 1) s += __shfl_xor(s, off, 64);
  if (lane == 0) red[4 + wv] = s;
  __syncthreads();
  float denom = red[4] + red[5] + red[6] + red[7] + __expf(qa - mx);
  float inv = 1.0f / denom;
  unsigned short h[16];
#pragma unroll
  for (int j = 0; j < 16; ++j) h[j] = f2bf(e[j] * inv);
  *(short8*)(row + t * 16) = *(short8*)h;
  *(short8*)(row + t * 16 + 8) = *(short8*)(h + 8);
}

// ---------------- gemm_o: out[4096][512] = q_v*q_att + P' * V  (K=4096) ----------------
// 128x64 tile, 8 waves (4m x 2n, 32x32 each), BK=128, double-buffered LDS,
// counted vmcnt(6) + raw s_barrier: next step's loads stay in flight under MFMA.
__global__ __launch_bounds__(512, 1) void gemm_o(const unsigned short* __restrict__ P,
                                                 const unsigned short* __restrict__ Vt,
                                                 const float* __restrict__ qatt,
                                                 const float* __restrict__ q_v,
                                                 float* __restrict__ out) {
  __shared__ __align__(16) char lds[98304];  // 2 x (A 32K + B 16K); epilogue reuses 32K
  const int tid = threadIdx.x;
  const int wid = tid >> 6, lane = tid & 63, lr = lane & 15, lh = lane >> 4;
  const int wm = wid >> 1, wn = wid & 1;  // 4 x 2 waves, 32x32 each

  int bid = blockIdx.x;                   // 256 WGs, 256%8==0
  int swz = (bid & 7) * 32 + (bid >> 3);
  const int tm = swz >> 3, tn = swz & 7;  // 32 x 8
  const size_t m0 = (size_t)tm * 128, n0 = (size_t)tn * 64;

  f32x4 acc[2][2];
#pragma unroll
  for (int i = 0; i < 2; ++i)
#pragma unroll
    for (int j = 0; j < 2; ++j) acc[i][j] = (f32x4){0.f, 0.f, 0.f, 0.f};

  const char* abase = (const char*)P + m0 * 8192;   // P row stride 8192 B
  const char* bbase = (const char*)Vt + n0 * 8192;  // Vt row stride 8192 B

  // stage K-step ks into buffer b: A tile 128x128bf16 (32KB, 256B rows) + B 64x128 (16KB)
  auto stage = [&](int ks, int b) {
    const int kb = ks * 256;  // 128 elems = 256 B
    char* al = lds + b * 49152;
    char* bl = al + 32768;
#pragma unroll
    for (int s = 0; s < 4; ++s) {
      int obase = wid * 4096 + s * 1024;  // 8 waves x 4KB, 1KB per GLL16 (fixed: was s*512)
      int o = obase + lane * 16;
      int row = o >> 8;                               // 256 B per LDS row
      int colg = ((o >> 4) & 15) ^ (row & 7);         // inverse-swizzled source granule
      GLL16(abase + (size_t)row * 8192 + kb + colg * 16, al + obase);
    }
#pragma unroll
    for (int s = 0; s < 2; ++s) {
      int obase = wid * 2048 + s * 1024;  // 8 waves x 2KB
      int o = obase + lane * 16;
      int row = o >> 8;
      int colg = ((o >> 4) & 15) ^ (row & 7);
      GLL16(bbase + (size_t)row * 8192 + kb + colg * 16, bl + obase);
    }
  };

  stage(0, 0);  // prologue: 6 outstanding

  for (int ks = 0; ks < 32; ++ks) {
    const int cur = ks & 1;
    if (ks + 1 < 32) {
      stage(ks + 1, cur ^ 1);                          // 6 more in flight (12 total)
      asm volatile("s_waitcnt vmcnt(6)" ::: "memory");  // current step's 6 landed
    } else {
      asm volatile("s_waitcnt vmcnt(0)" ::: "memory");
    }
    __builtin_amdgcn_s_barrier();
    asm volatile("" ::: "memory");

    const char* al = lds + cur * 49152;
    const char* bl = al + 32768;
#pragma unroll
    for (int kk = 0; kk < 4; ++kk) {
      short8 af[2], bf[2];
#pragma unroll
      for (int i = 0; i < 2; ++i) {
        int ar = wm * 32 + i * 16 + lr;
        af[i] = *(const short8*)(al + ar * 256 + ((((kk << 2) + lh) ^ (ar & 7)) << 4));
      }
#pragma unroll
      for (int j = 0; j < 2; ++j) {
        int br = wn * 32 + j * 16 + lr;
        bf[j] = *(const short8*)(bl + br * 256 + ((((kk << 2) + lh) ^ (br & 7)) << 4));
      }
#pragma unroll
      for (int i = 0; i < 2; ++i)
#pragma unroll
        for (int j = 0; j < 2; ++j)
          acc[i][j] = __builtin_amdgcn_mfma_f32_16x16x32_bf16(af[i], bf[j], acc[i][j], 0, 0, 0);
    }

    asm volatile("" ::: "memory");
    __builtin_amdgcn_s_barrier();  // all waves done reading buf[cur] before overwrite
    asm volatile("" ::: "memory");
  }

  // epilogue: f32 bounce [128][64] + fused  out = q_v*qa + acc
  float* fl = (float*)lds;
#pragma unroll
  for (int i = 0; i < 2; ++i)
#pragma unroll
    for (int j = 0; j < 2; ++j)
#pragma unroll
      for (int r = 0; r < 4; ++r) {
        int m = wm * 32 + i * 16 + lh * 4 + r;
        int n = wn * 32 + j * 16 + lr;
        fl[m * 64 + n] = acc[i][j][r];
      }
  __builtin_amdgcn_s_barrier();
  asm volatile("" ::: "memory");
#pragma unroll
  for (int i = 0; i < 4; ++i) {
    int o = i * 8192 + tid * 16;
    int row = o >> 8, colb = o & 255;  // 256 B per f32 tile row (64 floats)
    size_t gq = m0 + row;
    float qa = qatt[gq];
    float4 qv = *(const float4*)((const char*)q_v + gq * 2048 + n0 * 4 + colb);
    float4 a = *(const float4*)((const char*)fl + o);
    float4 r4 = {qv.x * qa + a.x, qv.y * qa + a.y, qv.z * qa + a.z, qv.w * qa + a.w};
    *(float4*)((char*)out + gq * 2048 + n0 * 4 + colb) = r4;
  }
}

extern "C" void kernel_launch(void* const* d_in, const int* in_sizes, int n_in,
                              void* d_out, int out_size, void* d_ws, size_t ws_size,
                              hipStream_t stream) {
  const float* query = (const float*)d_in[0];
  const float* q_k = (const float*)d_in[1];
  const float* q_v = (const float*)d_in[2];
  const float* key = (const float*)d_in[3];
  const float* value = (const float*)d_in[4];
  float* out = (float*)d_out;

  char* ws = (char*)d_ws;
  unsigned short* Qb = (unsigned short*)(ws);                 // 4 MB
  unsigned short* Kb = (unsigned short*)(ws + (4u << 20));    // 4 MB
  unsigned short* Vt = (unsigned short*)(ws + (8u << 20));    // 4 MB
  unsigned short* S = (unsigned short*)(ws + (12u << 20));    // 32 MB (S, then P' in-place)
  float* qatt = (float*)(ws + (44u << 20));                   // 16 KB

  prep_q<<<dim3(1024), dim3(256), 0, stream>>>(query, q_k, Qb, qatt);
  prep_k<<<dim3(1024), dim3(256), 0, stream>>>(key, Kb);
  prep_vt<<<dim3(128, 16), dim3(256), 0, stream>>>(value, Vt);
  gemm_s<<<dim3(1024), dim3(256), 0, stream>>>(Qb, Kb, S);
  softmax_rows<<<dim3(4096), dim3(256), 0, stream>>>(S, qatt);
  gemm_o<<<dim3(256), dim3(512), 0, stream>>>(S, Vt, qatt, q_v, out);
}